// Round 2
// baseline (12497.243 us; speedup 1.0000x reference)
//
#include <hip/hip_runtime.h>
#include <hip/hip_cooperative_groups.h>
#include <cstdint>

namespace cg = cooperative_groups;

// ---------------- problem constants ----------------
#define NYD   256
#define NXD   256
#define PMLW  20
#define PADC  22            // PML + FD_PAD
#define NYP_  300           // NY + 2*PAD
#define NXP_  300
#define GD    4             // zero guard ring width (covers radius-4 dependency)
#define ST    308           // padded stride = NYP_ + 2*GD
#define NTT   250
#define NSHOT_ 2
#define NSRC_  8
#define NREC_  64
#define DT_   0.0005f

// ---------------- zero workspace ----------------
__global__ void zero_kernel(float* __restrict__ p, long n) {
    long i = (long)blockIdx.x * blockDim.x + threadIdx.x;
    long stride = (long)gridDim.x * blockDim.x;
    for (; i < n; i += stride) p[i] = 0.0f;
}

// ---------------- one-time setup: v2dt2, PML profiles, src/rec masks ----------------
__global__ void populate_kernel(const float* __restrict__ v,
                                const int* __restrict__ srcloc,
                                const int* __restrict__ recloc,
                                float* __restrict__ v2dt2,
                                float* __restrict__ prof,   // [2*ST]: a (guarded), b (guarded)
                                unsigned* __restrict__ srcmask,
                                unsigned long long* __restrict__ recmask) {
    const long f = (long)ST * ST;
    int i = blockIdx.x * 256 + threadIdx.x;

    if (i < NYP_ * NXP_) {
        int y = i / NXP_, x = i % NXP_;
        int vy = min(max(y - PADC, 0), NYD - 1);
        int vx = min(max(x - PADC, 0), NXD - 1);
        float vv = v[vy * NXD + vx];
        v2dt2[(y + GD) * ST + (x + GD)] = vv * vv * (DT_ * DT_);
    }

    if (i < NYP_) {  // DY == DX and NYP == NXP, so one profile pair serves both axes
        float fi = (float)i;
        float d = fmaxf(22.0f - fi, fi - 277.0f);
        float frac = fminf(fmaxf(d * (1.0f / 20.0f), 0.0f), 1.0f);
        float sigma_max = 3.0f * 4000.0f * logf(1000.0f) / (2.0f * 20.0f * 5.0f);
        float sigma = sigma_max * frac * frac;
        float alpha = 3.14159265358979323846f * 25.0f * (1.0f - frac);
        float b = expf(-(sigma + alpha) * DT_);
        float a = sigma / (sigma + alpha + 1e-9f) * (b - 1.0f);
        prof[GD + i] = a;        // guard entries stay 0 from zero_kernel
        prof[ST + GD + i] = b;
    }

    if (i < NSHOT_ * NSRC_) {
        int sy = srcloc[2 * i] + PADC;
        int sx = srcloc[2 * i + 1] + PADC;
        int shot = i / NSRC_;
        int s = i % NSRC_;
        atomicOr(&srcmask[shot * f + (long)(sy + GD) * ST + (sx + GD)], 1u << s);
    }

    if (i >= 1024 && i < 1024 + NSHOT_ * NREC_) {
        int j = i - 1024;
        int ry = recloc[2 * j] + PADC;
        int rx = recloc[2 * j + 1] + PADC;
        int shot = j / NREC_;
        int r = j % NREC_;
        atomicOr(&recmask[shot * f + (long)(ry + GD) * ST + (rx + GD)], 1ull << r);
    }
}

// ---------------- persistent time loop (cooperative) ----------------
// One thread owns one (y,x) cell for BOTH shots across all 250 steps (shot
// loop fully unrolled -> static register indices). Time-invariant state (PML
// a/b, v2dt2, masks) and self-cell-only state (zeta, wfm) live in registers.
// wf and psi ping-pong in memory; one grid.sync() per step orders writes(t)
// before reads(t+1) (halo-recompute makes each step self-contained).
// Grid = 375 blocks; __launch_bounds__(256,2) guarantees >=2 blocks/CU
// (512-block cooperative capacity) with a huge VGPR margin -> no knife-edge.
__global__ __launch_bounds__(256, 2) void wave_kernel(
    float* __restrict__ wf0_all,   float* __restrict__ wf1_all,
    float* __restrict__ psiy0_all, float* __restrict__ psiy1_all,
    float* __restrict__ psix0_all, float* __restrict__ psix1_all,
    const float* __restrict__ v2dt2, const float* __restrict__ prof,
    const unsigned* __restrict__ srcmask,
    const unsigned long long* __restrict__ recmask,
    const float* __restrict__ amps,   // [NSHOT][NSRC][NT]
    float* __restrict__ out) {        // [NSHOT][NREC][NT]
    cg::grid_group grid = cg::this_grid();

    int x = blockIdx.x * 64 + threadIdx.x;
    const int y = blockIdx.y * 4 + threadIdx.y;   // grid.y*4 == 300 exactly
    bool active = (x < NXP_);
    if (!active) x = 0;                            // safe in-bounds dummy cell

    const long f = (long)ST * ST;
    const int c = (y + GD) * ST + (x + GD);

    // ---- loop-invariant state -> registers ----
    float ayv[5], byv[5], axv[5], bxv[5];
#pragma unroll
    for (int j = 0; j < 5; j++) {
        ayv[j] = prof[GD + y + j - 2];
        byv[j] = prof[ST + GD + y + j - 2];
        axv[j] = prof[GD + x + j - 2];
        bxv[j] = prof[ST + GD + x + j - 2];
    }
    const float vd = v2dt2[c];
    unsigned smv[2];
    unsigned long long rmv[2];
#pragma unroll
    for (int s = 0; s < 2; s++) {
        smv[s] = active ? srcmask[s * f + c] : 0u;
        rmv[s] = active ? recmask[s * f + c] : 0ull;
    }

    const float* wfr = wf0_all;   float* wfw = wf1_all;
    const float* pyr = psiy0_all; float* pyw = psiy1_all;
    const float* pxr = psix0_all; float* pxw = psix1_all;

    float zy[2] = {0.0f, 0.0f}, zx[2] = {0.0f, 0.0f}, wfm[2] = {0.0f, 0.0f};

    const float inv_h  = 0.2f;    // 1/DY
    const float inv_h2 = 0.04f;   // 1/DY^2
    const float C1A = 2.0f / 3.0f, C1B = 1.0f / 12.0f;
    const float C2A = 4.0f / 3.0f, C2B = -1.0f / 12.0f, C2C = -2.5f;

    for (int t = 0; t < NTT; t++) {
#pragma unroll
        for (int s = 0; s < 2; s++) {
            const float* wfc = wfr + s * f;
            const float* pyc = pyr + s * f;
            const float* pxc = pxr + s * f;

            float wy[9], wx[9];
#pragma unroll
            for (int k = 0; k < 9; k++) wy[k] = wfc[c + (k - 4) * ST];
#pragma unroll
            for (int k = 0; k < 9; k++) wx[k] = (k == 4) ? wy[4] : wfc[c + (k - 4)];

            float d2y = (C2B * (wy[2] + wy[6]) + C2A * (wy[3] + wy[5]) + C2C * wy[4]) * inv_h2;
            float d2x = (C2B * (wx[2] + wx[6]) + C2A * (wx[3] + wx[5]) + C2C * wx[4]) * inv_h2;

            float pny[5], pnx[5];
#pragma unroll
            for (int j = 0; j < 5; j++) {
                float dwdy = (C1A * (wy[j + 3] - wy[j + 1]) - C1B * (wy[j + 4] - wy[j])) * inv_h;
                float dwdx = (C1A * (wx[j + 3] - wx[j + 1]) - C1B * (wx[j + 4] - wx[j])) * inv_h;
                pny[j] = byv[j] * pyc[c + (j - 2) * ST] + ayv[j] * dwdy;
                pnx[j] = bxv[j] * pxc[c + (j - 2)]      + axv[j] * dwdx;
            }

            float dpsiy = (C1A * (pny[3] - pny[1]) - C1B * (pny[4] - pny[0])) * inv_h;
            float dpsix = (C1A * (pnx[3] - pnx[1]) - C1B * (pnx[4] - pnx[0])) * inv_h;

            zy[s] = byv[2] * zy[s] + ayv[2] * (d2y + dpsiy);
            zx[s] = bxv[2] * zx[s] + axv[2] * (d2x + dpsix);

            float lap = d2y + d2x + dpsiy + dpsix + zy[s] + zx[s];
            float wfp = 2.0f * wy[4] - wfm[s] + vd * lap;

            // source injection (owner thread), before store & record — matches reference
            if (smv[s]) {
#pragma unroll
                for (int q = 0; q < NSRC_; q++)
                    if (smv[s] & (1u << q)) wfp += vd * amps[(s * NSRC_ + q) * NTT + t];
            }

            if (active) {
                wfw[s * f + c] = wfp;
                pyw[s * f + c] = pny[2];
                pxw[s * f + c] = pnx[2];
            }

            unsigned long long r = rmv[s];
            while (r) {
                int rr = __ffsll(r) - 1;
                out[(s * NREC_ + rr) * NTT + t] = wfp;
                r &= r - 1;
            }

            wfm[s] = wy[4];   // this step's wfc becomes next step's wfm
        }

        grid.sync();   // writes(t) visible before reads(t+1); one barrier suffices

        // ping-pong
        const float* tw = wfr; wfr = wfw; wfw = (float*)tw;
        const float* ty = pyr; pyr = pyw; pyw = (float*)ty;
        const float* tx = pxr; pxr = pxw; pxw = (float*)tx;
    }
}

// ---------------- fallback: one time step per launch (known-good baseline) ----------------
__global__ __launch_bounds__(256) void step_kernel(
    const float* __restrict__ wfc_all,  float* __restrict__ wfn_all,   // read wfm / write wfp
    const float* __restrict__ psiyr_all, float* __restrict__ psiyw_all,
    const float* __restrict__ psixr_all, float* __restrict__ psixw_all,
    float* __restrict__ zetay_all, float* __restrict__ zetax_all,
    const float* __restrict__ v2dt2, const float* __restrict__ prof,
    const unsigned* __restrict__ srcmask,
    const unsigned long long* __restrict__ recmask,
    const float* __restrict__ amps,   // [NSHOT][NSRC][NT]
    float* __restrict__ out,          // [NSHOT][NREC][NT]
    int t) {
    int x = blockIdx.x * 64 + threadIdx.x;
    int y = blockIdx.y * 4 + threadIdx.y;
    int shot = blockIdx.z;
    if (x >= NXP_ || y >= NYP_) return;

    const long f = (long)ST * ST;
    const float* wfc   = wfc_all   + shot * f;
    float*       wfn   = wfn_all   + shot * f;
    const float* psiyr = psiyr_all + shot * f;
    float*       psiyw = psiyw_all + shot * f;
    const float* psixr = psixr_all + shot * f;
    float*       psixw = psixw_all + shot * f;
    float*       zetay = zetay_all + shot * f;
    float*       zetax = zetax_all + shot * f;

    const int c = (y + GD) * ST + (x + GD);

    float wy[9], wx[9];
#pragma unroll
    for (int k = 0; k < 9; k++) wy[k] = wfc[c + (k - 4) * ST];
#pragma unroll
    for (int k = 0; k < 9; k++) wx[k] = (k == 4) ? wy[4] : wfc[c + (k - 4)];

    const float inv_h  = 0.2f;
    const float inv_h2 = 0.04f;
    const float C1A = 2.0f / 3.0f, C1B = 1.0f / 12.0f;
    const float C2A = 4.0f / 3.0f, C2B = -1.0f / 12.0f, C2C = -2.5f;

    float d2y = (C2B * (wy[2] + wy[6]) + C2A * (wy[3] + wy[5]) + C2C * wy[4]) * inv_h2;
    float d2x = (C2B * (wx[2] + wx[6]) + C2A * (wx[3] + wx[5]) + C2C * wx[4]) * inv_h2;

    float dwdy[5], dwdx[5];
#pragma unroll
    for (int j = 0; j < 5; j++) {
        dwdy[j] = (C1A * (wy[j + 3] - wy[j + 1]) - C1B * (wy[j + 4] - wy[j])) * inv_h;
        dwdx[j] = (C1A * (wx[j + 3] - wx[j + 1]) - C1B * (wx[j + 4] - wx[j])) * inv_h;
    }

    float pny[5], pnx[5];
#pragma unroll
    for (int j = 0; j < 5; j++) {
        int yy = y + j - 2;
        float ayj = prof[GD + yy];
        float byj = prof[ST + GD + yy];
        pny[j] = byj * psiyr[c + (j - 2) * ST] + ayj * dwdy[j];
        int xx = x + j - 2;
        float axj = prof[GD + xx];
        float bxj = prof[ST + GD + xx];
        pnx[j] = bxj * psixr[c + (j - 2)] + axj * dwdx[j];
    }

    float dpsiy = (C1A * (pny[3] - pny[1]) - C1B * (pny[4] - pny[0])) * inv_h;
    float dpsix = (C1A * (pnx[3] - pnx[1]) - C1B * (pnx[4] - pnx[0])) * inv_h;

    float ay_ = prof[GD + y], by_ = prof[ST + GD + y];
    float ax_ = prof[GD + x], bx_ = prof[ST + GD + x];

    float zy = by_ * zetay[c] + ay_ * (d2y + dpsiy);
    float zx = bx_ * zetax[c] + ax_ * (d2x + dpsix);

    float lap = d2y + d2x + dpsiy + dpsix + zy + zx;
    float vd  = v2dt2[(y + GD) * ST + (x + GD)];
    float wfp = 2.0f * wy[4] - wfn[c] + vd * lap;

    unsigned sm = srcmask[shot * f + c];
    if (sm) {
#pragma unroll
        for (int s = 0; s < NSRC_; s++)
            if (sm & (1u << s)) wfp += vd * amps[(shot * NSRC_ + s) * NTT + t];
    }

    wfn[c]   = wfp;
    psiyw[c] = pny[2];
    psixw[c] = pnx[2];
    zetay[c] = zy;
    zetax[c] = zx;

    unsigned long long rm = recmask[shot * f + c];
    while (rm) {
        int r = __ffsll((unsigned long long)rm) - 1;
        out[(shot * NREC_ + r) * NTT + t] = wfp;
        rm &= rm - 1;
    }
}

// ---------------- host ----------------
extern "C" void kernel_launch(void* const* d_in, const int* in_sizes, int n_in,
                              void* d_out, int out_size, void* d_ws, size_t ws_size,
                              hipStream_t stream) {
    const float* v      = (const float*)d_in[0];
    const float* amps   = (const float*)d_in[1];
    const int*   srcloc = (const int*)d_in[2];
    const int*   recloc = (const int*)d_in[3];
    float* out = (float*)d_out;

    const long f = (long)ST * ST;
    float* base  = (float*)d_ws;
    float* wf0   = base;             // 2 shots each
    float* wf1   = wf0   + 2 * f;
    float* psiy0 = wf1   + 2 * f;
    float* psiy1 = psiy0 + 2 * f;
    float* psix0 = psiy1 + 2 * f;
    float* psix1 = psix0 + 2 * f;
    float* zetay = psix1 + 2 * f;    // only used by fallback path
    float* zetax = zetay + 2 * f;
    float* v2dt2 = zetax + 2 * f;    // f (shot-independent)
    float* prof  = v2dt2 + f;        // 2*ST
    unsigned* srcmask = (unsigned*)(prof + 2 * ST);                        // 2f uints
    unsigned long long* recmask = (unsigned long long*)(srcmask + 2 * f);  // 2f ull

    const long total_words = 23 * f + 2 * ST;  // fields + zeta + v2dt2 + prof + masks

    zero_kernel<<<4096, 256, 0, stream>>>(base, total_words);
    populate_kernel<<<(NYP_ * NXP_ + 255) / 256, 256, 0, stream>>>(
        v, srcloc, recloc, v2dt2, prof, srcmask, recmask);

    // ---- preferred: single persistent cooperative kernel ----
    dim3 blk(64, 4, 1);
    dim3 grd(5, 75, 1);   // 375 blocks <= 512-block capacity at 2 blk/CU

    void* args[] = {
        (void*)&wf0, (void*)&wf1, (void*)&psiy0, (void*)&psiy1,
        (void*)&psix0, (void*)&psix1, (void*)&v2dt2, (void*)&prof,
        (void*)&srcmask, (void*)&recmask, (void*)&amps, (void*)&out
    };
    hipError_t e = hipLaunchCooperativeKernel((void*)wave_kernel, grd, blk, args, 0, stream);

    // ---- fallback: known-good 250-launch loop ----
    if (e != hipSuccess) {
        dim3 grd2((NXP_ + 63) / 64, (NYP_ + 3) / 4, NSHOT_);
        for (int t = 0; t < NTT; t++) {
            const float* wc  = (t & 1) ? wf1 : wf0;
            float*       wn  = (t & 1) ? wf0 : wf1;
            const float* pyr = (t & 1) ? psiy1 : psiy0;
            float*       pyw = (t & 1) ? psiy0 : psiy1;
            const float* pxr = (t & 1) ? psix1 : psix0;
            float*       pxw = (t & 1) ? psix0 : psix1;
            step_kernel<<<grd2, blk, 0, stream>>>(wc, wn, pyr, pyw, pxr, pxw,
                                                  zetay, zetax, v2dt2, prof,
                                                  srcmask, recmask, amps, out, t);
        }
    }
}

// Round 3
// 1516.479 us; speedup vs baseline: 8.2410x; 8.2410x over previous
//
#include <hip/hip_runtime.h>
#include <cstdint>

// ---------------- problem constants ----------------
#define NYD   256
#define NXD   256
#define PADC  22            // PML + FD_PAD
#define NYP_  300           // NY + 2*PAD
#define NXP_  300
#define NTT   250
#define NSHOT_ 2
#define NSRC_  8
#define NREC_  64
#define DT_   0.0005f

// fused-path geometry
#define GD2   12            // guard ring (covers tile halo radius 8 + psi region overshoot)
#define ST2   324           // NXP_ + 2*GD2
#define TSZ   16            // output tile edge
#define NTILE 19            // ceil(300/16)
// legacy-path geometry (round-0 proven kernel)
#define LGD   4
#define LST   308

// ---------------- zero workspace ----------------
__global__ void zero_kernel(float* __restrict__ p, long n) {
    long i = (long)blockIdx.x * blockDim.x + threadIdx.x;
    long stride = (long)gridDim.x * blockDim.x;
    for (; i < n; i += stride) p[i] = 0.0f;
}

// ---------------- fused-path setup: v2dt2, PML profiles, receiver tile bins ----------------
__global__ void populate2_kernel(const float* __restrict__ v,
                                 const int* __restrict__ recloc,
                                 float* __restrict__ v2dt2,
                                 float* __restrict__ prof,   // [2*ST2]: a, b (guarded)
                                 unsigned long long* __restrict__ recbin) { // [NSHOT][NTILE*NTILE]
    int i = blockIdx.x * 256 + threadIdx.x;

    if (i < NYP_ * NXP_) {
        int y = i / NXP_, x = i % NXP_;
        int vy = min(max(y - PADC, 0), NYD - 1);
        int vx = min(max(x - PADC, 0), NXD - 1);
        float vv = v[vy * NXD + vx];
        v2dt2[(y + GD2) * ST2 + (x + GD2)] = vv * vv * (DT_ * DT_);
    }

    if (i < NYP_) {  // DY == DX and NYP == NXP: one profile pair serves both axes
        float fi = (float)i;
        float d = fmaxf(22.0f - fi, fi - 277.0f);
        float frac = fminf(fmaxf(d * (1.0f / 20.0f), 0.0f), 1.0f);
        float sigma_max = 3.0f * 4000.0f * logf(1000.0f) / (2.0f * 20.0f * 5.0f);
        float sigma = sigma_max * frac * frac;
        float alpha = 3.14159265358979323846f * 25.0f * (1.0f - frac);
        float b = expf(-(sigma + alpha) * DT_);
        float a = sigma / (sigma + alpha + 1e-9f) * (b - 1.0f);
        prof[GD2 + i] = a;          // guard entries stay 0
        prof[ST2 + GD2 + i] = b;
    }

    if (i < NSHOT_ * NREC_) {
        int ry = recloc[2 * i] + PADC;      // padded coords, [22,278)
        int rx = recloc[2 * i + 1] + PADC;
        int shot = i / NREC_;
        int r = i % NREC_;
        int tile = (ry / TSZ) * NTILE + (rx / TSZ);
        atomicOr(&recbin[shot * (NTILE * NTILE) + tile], 1ull << r);
    }
}

// ---------------- fused kernel: 2 time steps per launch ----------------
// Per 16x16 output tile: stage wf(t) 32x32 in LDS; compute psi(t+1) once per
// cell into LDS (phase A), wf(t+1)+zeta(t+1) on the 24x24 S1 region (phase B,
// sources injected anywhere in region), then step 2 per output cell with the
// proven +/-2 psi halo-recompute (phase C). All fields ping-pong across
// launches (wf uses 4 buffers) so no cross-block races. Guard ring GD2=12 is
// always zero => zero-Dirichlet FD boundaries with no bounds checks.
__global__ __launch_bounds__(256) void fused2_kernel(
    const float* __restrict__ wfm_all,  // wf(t-1)
    const float* __restrict__ wfc_all,  // wf(t)
    float* __restrict__ wf1_all,        // out: wf(t+1)
    float* __restrict__ wf2_all,        // out: wf(t+2)
    const float* __restrict__ pyR_all, float* __restrict__ pyW_all,
    const float* __restrict__ pxR_all, float* __restrict__ pxW_all,
    const float* __restrict__ zyR_all, float* __restrict__ zyW_all,
    const float* __restrict__ zxR_all, float* __restrict__ zxW_all,
    const float* __restrict__ v2, const float* __restrict__ prof,
    const unsigned long long* __restrict__ recbin,
    const int* __restrict__ srcloc, const int* __restrict__ recloc,
    const float* __restrict__ amps,   // [NSHOT][NSRC][NT]
    float* __restrict__ out,          // [NSHOT][NREC][NT]
    int t) {
    const int tid  = threadIdx.x;
    const int shot = blockIdx.z;
    const int by0  = blockIdx.y * TSZ;
    const int bx0  = blockIdx.x * TSZ;
    const int f    = ST2 * ST2;

    __shared__ float swf [32][33];   // wf(t), rel y,x in [-8,24)
    __shared__ float spy1[28][25];   // psiy(t+1), y in [-6,22), x in [-4,20)
    __shared__ float spx1[24][29];   // psix(t+1), y in [-4,20), x in [-6,22)
    __shared__ float swf1[24][25];   // wf(t+1),  y,x in [-4,20)
    __shared__ float szy1[16][17];   // zetay(t+1) at output cells
    __shared__ float szx1[16][17];
    __shared__ int   ssrc[2][NSRC_];
    __shared__ int   srec[2][NREC_];
    __shared__ unsigned long long srbin;

    const float* wfmg = wfm_all + shot * f;
    const float* wfcg = wfc_all + shot * f;
    float*       w1g  = wf1_all + shot * f;
    float*       w2g  = wf2_all + shot * f;
    const float* pyR  = pyR_all + shot * f;
    float*       pyW  = pyW_all + shot * f;
    const float* pxR  = pxR_all + shot * f;
    float*       pxW  = pxW_all + shot * f;
    const float* zyR  = zyR_all + shot * f;
    float*       zyW  = zyW_all + shot * f;
    const float* zxR  = zxR_all + shot * f;
    float*       zxW  = zxW_all + shot * f;

    const float ih  = 0.2f;    // 1/DY
    const float ih2 = 0.04f;   // 1/DY^2
    const float C1A = 2.0f / 3.0f, C1B = 1.0f / 12.0f;
    const float C2A = 4.0f / 3.0f, C2B = -1.0f / 12.0f, C2C = -2.5f;

    // ---- phase 0: stage wf(t), load src/rec lists ----
#pragma unroll
    for (int k = 0; k < 4; k++) {
        int lin = tid + k * 256;
        int r = lin >> 5, c = lin & 31;
        swf[r][c] = wfcg[(by0 + r - 8 + GD2) * ST2 + (bx0 + c - 8 + GD2)];
    }
    if (tid < NSRC_) {
        ssrc[0][tid] = srcloc[(shot * NSRC_ + tid) * 2]     + PADC;
        ssrc[1][tid] = srcloc[(shot * NSRC_ + tid) * 2 + 1] + PADC;
    }
    if (tid < NREC_) {
        srec[0][tid] = recloc[(shot * NREC_ + tid) * 2]     + PADC;
        srec[1][tid] = recloc[(shot * NREC_ + tid) * 2 + 1] + PADC;
    }
    if (tid == 0) srbin = recbin[shot * (NTILE * NTILE) + blockIdx.y * NTILE + blockIdx.x];
    __syncthreads();

    // ---- phase A: psi(t+1) into LDS ----
    // psiy1: rows r=y+6 (y in [-6,22)), cols c=x+4 (x in [-4,20))  [28x24]
#pragma unroll
    for (int k = 0; k < 3; k++) {
        int lin = tid + k * 256;
        if (lin < 28 * 24) {
            int r = lin / 24, c = lin % 24;
            int gy = by0 + r - 6, gx = bx0 + c - 4;
            // swf center row = (r-6)+8 = r+2, col = (c-4)+8 = c+4
            float dw = (C1A * (swf[r + 3][c + 4] - swf[r + 1][c + 4])
                      - C1B * (swf[r + 4][c + 4] - swf[r][c + 4])) * ih;
            float a = prof[GD2 + gy], b = prof[ST2 + GD2 + gy];
            spy1[r][c] = b * pyR[(gy + GD2) * ST2 + (gx + GD2)] + a * dw;
        }
    }
    // psix1: rows r=y+4 (y in [-4,20)), cols c=x+6 (x in [-6,22))  [24x28]
#pragma unroll
    for (int k = 0; k < 3; k++) {
        int lin = tid + k * 256;
        if (lin < 24 * 28) {
            int r = lin / 28, c = lin % 28;
            int gy = by0 + r - 4, gx = bx0 + c - 6;
            // swf row = r+4, center col = (c-6)+8 = c+2
            float dw = (C1A * (swf[r + 4][c + 3] - swf[r + 4][c + 1])
                      - C1B * (swf[r + 4][c + 4] - swf[r + 4][c])) * ih;
            float a = prof[GD2 + gx], b = prof[ST2 + GD2 + gx];
            spx1[r][c] = b * pxR[(gy + GD2) * ST2 + (gx + GD2)] + a * dw;
        }
    }
    __syncthreads();

    // ---- phase B: wf(t+1) + zeta(t+1) on S1 = [-4,20)^2 ----
#pragma unroll
    for (int k = 0; k < 3; k++) {
        int lin = tid + k * 256;
        if (lin < 24 * 24) {
            int r = lin / 24, c = lin % 24;        // y=r-4, x=c-4
            int gy = by0 + r - 4, gx = bx0 + c - 4;
            float wc = swf[r + 4][c + 4];
            float d2y = (C2B * (swf[r + 2][c + 4] + swf[r + 6][c + 4])
                       + C2A * (swf[r + 3][c + 4] + swf[r + 5][c + 4]) + C2C * wc) * ih2;
            float d2x = (C2B * (swf[r + 4][c + 2] + swf[r + 4][c + 6])
                       + C2A * (swf[r + 4][c + 3] + swf[r + 4][c + 5]) + C2C * wc) * ih2;
            // dpsiy1: spy1 row for y is y+6 = r+2; taps +/-1,+/-2 -> r+1,r+3,r,r+4; col = x+4 = c
            float dpy = (C1A * (spy1[r + 3][c] - spy1[r + 1][c])
                       - C1B * (spy1[r + 4][c] - spy1[r][c])) * ih;
            // dpsix1: spx1 row = y+4 = r; col for x is x+6 = c+2; taps -> c+1,c+3,c,c+4
            float dpx = (C1A * (spx1[r][c + 3] - spx1[r][c + 1])
                       - C1B * (spx1[r][c + 4] - spx1[r][c])) * ih;
            int g = (gy + GD2) * ST2 + (gx + GD2);
            float ay = prof[GD2 + gy], by = prof[ST2 + GD2 + gy];
            float ax = prof[GD2 + gx], bx = prof[ST2 + GD2 + gx];
            float zy1 = by * zyR[g] + ay * (d2y + dpy);
            float zx1 = bx * zxR[g] + ax * (d2x + dpx);
            float vdd = v2[g];
            float w1 = 2.0f * wc - wfmg[g] + vdd * (d2y + d2x + dpy + dpx + zy1 + zx1);
#pragma unroll
            for (int q = 0; q < NSRC_; q++)
                if (gy == ssrc[0][q] && gx == ssrc[1][q])
                    w1 += vdd * amps[(shot * NSRC_ + q) * NTT + t];
            swf1[r][c] = w1;
            if (r >= 4 && r < 20 && c >= 4 && c < 20) {
                szy1[r - 4][c - 4] = zy1;
                szx1[r - 4][c - 4] = zx1;
            }
        }
    }
    __syncthreads();

    // ---- phase C: step 2 at output cell (1 per thread) ----
    {
        int y = tid >> 4, x = tid & 15;
        int gy = by0 + y, gx = bx0 + x;
        float w1c = swf1[y + 4][x + 4];
        float wcc = swf[y + 8][x + 8];
        float d2y1 = (C2B * (swf1[y + 2][x + 4] + swf1[y + 6][x + 4])
                    + C2A * (swf1[y + 3][x + 4] + swf1[y + 5][x + 4]) + C2C * w1c) * ih2;
        float d2x1 = (C2B * (swf1[y + 4][x + 2] + swf1[y + 4][x + 6])
                    + C2A * (swf1[y + 4][x + 3] + swf1[y + 4][x + 5]) + C2C * w1c) * ih2;
        float py2[5], px2[5];
#pragma unroll
        for (int j = 0; j < 5; j++) {
            int yp = y + j - 2, gyp = by0 + yp;
            float dw1 = (C1A * (swf1[yp + 5][x + 4] - swf1[yp + 3][x + 4])
                       - C1B * (swf1[yp + 6][x + 4] - swf1[yp + 2][x + 4])) * ih;
            py2[j] = prof[ST2 + GD2 + gyp] * spy1[yp + 6][x + 4] + prof[GD2 + gyp] * dw1;
            int xp = x + j - 2, gxp = bx0 + xp;
            float dx1 = (C1A * (swf1[y + 4][xp + 5] - swf1[y + 4][xp + 3])
                       - C1B * (swf1[y + 4][xp + 6] - swf1[y + 4][xp + 2])) * ih;
            px2[j] = prof[ST2 + GD2 + gxp] * spx1[y + 4][xp + 6] + prof[GD2 + gxp] * dx1;
        }
        float dpy2 = (C1A * (py2[3] - py2[1]) - C1B * (py2[4] - py2[0])) * ih;
        float dpx2 = (C1A * (px2[3] - px2[1]) - C1B * (px2[4] - px2[0])) * ih;
        float ay = prof[GD2 + gy], by = prof[ST2 + GD2 + gy];
        float ax = prof[GD2 + gx], bx = prof[ST2 + GD2 + gx];
        float zy2 = by * szy1[y][x] + ay * (d2y1 + dpy2);
        float zx2 = bx * szx1[y][x] + ax * (d2x1 + dpx2);
        int g = (gy + GD2) * ST2 + (gx + GD2);
        float vdd = v2[g];
        float w2 = 2.0f * w1c - wcc + vdd * (d2y1 + d2x1 + dpy2 + dpx2 + zy2 + zx2);
#pragma unroll
        for (int q = 0; q < NSRC_; q++)
            if (gy == ssrc[0][q] && gx == ssrc[1][q])
                w2 += vdd * amps[(shot * NSRC_ + q) * NTT + t + 1];

        if (gy < NYP_ && gx < NXP_) {
            w1g[g] = w1c;
            w2g[g] = w2;
            pyW[g] = py2[2];
            pxW[g] = px2[2];
            zyW[g] = zy2;
            zxW[g] = zx2;
            unsigned long long rb = srbin;
            while (rb) {
                int rr = __ffsll(rb) - 1;
                rb &= rb - 1;
                if (srec[0][rr] == gy && srec[1][rr] == gx) {
                    out[(shot * NREC_ + rr) * NTT + t]     = w1c;
                    out[(shot * NREC_ + rr) * NTT + t + 1] = w2;
                }
            }
        }
    }
}

// ================= legacy path (round-0 proven kernel, ws-size fallback) =================
__global__ void populateL_kernel(const float* __restrict__ v,
                                 const int* __restrict__ srcloc,
                                 const int* __restrict__ recloc,
                                 float* __restrict__ v2dt2,
                                 float* __restrict__ prof,
                                 unsigned* __restrict__ srcmask,
                                 unsigned long long* __restrict__ recmask) {
    const long f = (long)LST * LST;
    int i = blockIdx.x * 256 + threadIdx.x;
    if (i < NYP_ * NXP_) {
        int y = i / NXP_, x = i % NXP_;
        int vy = min(max(y - PADC, 0), NYD - 1);
        int vx = min(max(x - PADC, 0), NXD - 1);
        float vv = v[vy * NXD + vx];
        v2dt2[(y + LGD) * LST + (x + LGD)] = vv * vv * (DT_ * DT_);
    }
    if (i < NYP_) {
        float fi = (float)i;
        float d = fmaxf(22.0f - fi, fi - 277.0f);
        float frac = fminf(fmaxf(d * (1.0f / 20.0f), 0.0f), 1.0f);
        float sigma_max = 3.0f * 4000.0f * logf(1000.0f) / (2.0f * 20.0f * 5.0f);
        float sigma = sigma_max * frac * frac;
        float alpha = 3.14159265358979323846f * 25.0f * (1.0f - frac);
        float b = expf(-(sigma + alpha) * DT_);
        float a = sigma / (sigma + alpha + 1e-9f) * (b - 1.0f);
        prof[LGD + i] = a;
        prof[LST + LGD + i] = b;
    }
    if (i < NSHOT_ * NSRC_) {
        int sy = srcloc[2 * i] + PADC;
        int sx = srcloc[2 * i + 1] + PADC;
        atomicOr(&srcmask[(i / NSRC_) * f + (long)(sy + LGD) * LST + (sx + LGD)], 1u << (i % NSRC_));
    }
    if (i >= 1024 && i < 1024 + NSHOT_ * NREC_) {
        int j = i - 1024;
        int ry = recloc[2 * j] + PADC;
        int rx = recloc[2 * j + 1] + PADC;
        atomicOr(&recmask[(j / NREC_) * f + (long)(ry + LGD) * LST + (rx + LGD)], 1ull << (j % NREC_));
    }
}

__global__ __launch_bounds__(256) void stepL_kernel(
    const float* __restrict__ wfc_all,  float* __restrict__ wfn_all,
    const float* __restrict__ psiyr_all, float* __restrict__ psiyw_all,
    const float* __restrict__ psixr_all, float* __restrict__ psixw_all,
    float* __restrict__ zetay_all, float* __restrict__ zetax_all,
    const float* __restrict__ v2dt2, const float* __restrict__ prof,
    const unsigned* __restrict__ srcmask,
    const unsigned long long* __restrict__ recmask,
    const float* __restrict__ amps, float* __restrict__ out, int t) {
    int x = blockIdx.x * 64 + threadIdx.x;
    int y = blockIdx.y * 4 + threadIdx.y;
    int shot = blockIdx.z;
    if (x >= NXP_ || y >= NYP_) return;
    const long f = (long)LST * LST;
    const float* wfc   = wfc_all   + shot * f;
    float*       wfn   = wfn_all   + shot * f;
    const float* psiyr = psiyr_all + shot * f;
    float*       psiyw = psiyw_all + shot * f;
    const float* psixr = psixr_all + shot * f;
    float*       psixw = psixw_all + shot * f;
    float*       zetay = zetay_all + shot * f;
    float*       zetax = zetax_all + shot * f;
    const int c = (y + LGD) * LST + (x + LGD);
    float wy[9], wx[9];
#pragma unroll
    for (int k = 0; k < 9; k++) wy[k] = wfc[c + (k - 4) * LST];
#pragma unroll
    for (int k = 0; k < 9; k++) wx[k] = (k == 4) ? wy[4] : wfc[c + (k - 4)];
    const float ih = 0.2f, ih2 = 0.04f;
    const float C1A = 2.0f / 3.0f, C1B = 1.0f / 12.0f;
    const float C2A = 4.0f / 3.0f, C2B = -1.0f / 12.0f, C2C = -2.5f;
    float d2y = (C2B * (wy[2] + wy[6]) + C2A * (wy[3] + wy[5]) + C2C * wy[4]) * ih2;
    float d2x = (C2B * (wx[2] + wx[6]) + C2A * (wx[3] + wx[5]) + C2C * wx[4]) * ih2;
    float dwdy[5], dwdx[5];
#pragma unroll
    for (int j = 0; j < 5; j++) {
        dwdy[j] = (C1A * (wy[j + 3] - wy[j + 1]) - C1B * (wy[j + 4] - wy[j])) * ih;
        dwdx[j] = (C1A * (wx[j + 3] - wx[j + 1]) - C1B * (wx[j + 4] - wx[j])) * ih;
    }
    float pny[5], pnx[5];
#pragma unroll
    for (int j = 0; j < 5; j++) {
        int yy = y + j - 2;
        pny[j] = prof[LST + LGD + yy] * psiyr[c + (j - 2) * LST] + prof[LGD + yy] * dwdy[j];
        int xx = x + j - 2;
        pnx[j] = prof[LST + LGD + xx] * psixr[c + (j - 2)] + prof[LGD + xx] * dwdx[j];
    }
    float dpsiy = (C1A * (pny[3] - pny[1]) - C1B * (pny[4] - pny[0])) * ih;
    float dpsix = (C1A * (pnx[3] - pnx[1]) - C1B * (pnx[4] - pnx[0])) * ih;
    float ay_ = prof[LGD + y], by_ = prof[LST + LGD + y];
    float ax_ = prof[LGD + x], bx_ = prof[LST + LGD + x];
    float zy = by_ * zetay[c] + ay_ * (d2y + dpsiy);
    float zx = bx_ * zetax[c] + ax_ * (d2x + dpsix);
    float lap = d2y + d2x + dpsiy + dpsix + zy + zx;
    float vd  = v2dt2[(y + LGD) * LST + (x + LGD)];
    float wfp = 2.0f * wy[4] - wfn[c] + vd * lap;
    unsigned sm = srcmask[shot * f + c];
    if (sm) {
#pragma unroll
        for (int s = 0; s < NSRC_; s++)
            if (sm & (1u << s)) wfp += vd * amps[(shot * NSRC_ + s) * NTT + t];
    }
    wfn[c]   = wfp;
    psiyw[c] = pny[2];
    psixw[c] = pnx[2];
    zetay[c] = zy;
    zetax[c] = zx;
    unsigned long long rm = recmask[shot * f + c];
    while (rm) {
        int r = __ffsll(rm) - 1;
        out[(shot * NREC_ + r) * NTT + t] = wfp;
        rm &= rm - 1;
    }
}

// ---------------- host ----------------
extern "C" void kernel_launch(void* const* d_in, const int* in_sizes, int n_in,
                              void* d_out, int out_size, void* d_ws, size_t ws_size,
                              hipStream_t stream) {
    const float* v      = (const float*)d_in[0];
    const float* amps   = (const float*)d_in[1];
    const int*   srcloc = (const int*)d_in[2];
    const int*   recloc = (const int*)d_in[3];
    float* out = (float*)d_out;
    float* base = (float*)d_ws;

    const long f2 = (long)ST2 * ST2;
    const long nbins = NSHOT_ * NTILE * NTILE;                  // 722
    const long fused_words = 25 * f2 + 2 * ST2 + 2 * nbins;     // recbin = 2 words each
    const bool use_fused = ws_size >= (size_t)(fused_words * 4);

    if (use_fused) {
        float* W0 = base;            // wf buffers, 2 shots each
        float* W1 = W0 + 2 * f2;
        float* W2 = W1 + 2 * f2;
        float* W3 = W2 + 2 * f2;
        float* PY0 = W3 + 2 * f2;
        float* PY1 = PY0 + 2 * f2;
        float* PX0 = PY1 + 2 * f2;
        float* PX1 = PX0 + 2 * f2;
        float* ZY0 = PX1 + 2 * f2;
        float* ZY1 = ZY0 + 2 * f2;
        float* ZX0 = ZY1 + 2 * f2;
        float* ZX1 = ZX0 + 2 * f2;
        float* v2  = ZX1 + 2 * f2;   // f2, shot-independent
        float* prof = v2 + f2;       // 2*ST2
        unsigned long long* recbin = (unsigned long long*)(prof + 2 * ST2);

        zero_kernel<<<2048, 256, 0, stream>>>(base, fused_words);
        populate2_kernel<<<(NYP_ * NXP_ + 255) / 256, 256, 0, stream>>>(
            v, recloc, v2, prof, recbin);

        dim3 blk(256, 1, 1);
        dim3 grd(NTILE, NTILE, NSHOT_);
        for (int k = 0; k < NTT / 2; k++) {
            const bool o = (k & 1);
            fused2_kernel<<<grd, blk, 0, stream>>>(
                o ? W2 : W0, o ? W3 : W1,   // wfm, wfc
                o ? W0 : W2, o ? W1 : W3,   // wf(t+1), wf(t+2)
                o ? PY1 : PY0, o ? PY0 : PY1,
                o ? PX1 : PX0, o ? PX0 : PX1,
                o ? ZY1 : ZY0, o ? ZY0 : ZY1,
                o ? ZX1 : ZX0, o ? ZX0 : ZX1,
                v2, prof, recbin, srcloc, recloc, amps, out, 2 * k);
        }
    } else {
        // legacy round-0 path
        const long f = (long)LST * LST;
        float* wf0   = base;
        float* wf1   = wf0   + 2 * f;
        float* psiy0 = wf1   + 2 * f;
        float* psiy1 = psiy0 + 2 * f;
        float* psix0 = psiy1 + 2 * f;
        float* psix1 = psix0 + 2 * f;
        float* zetay = psix1 + 2 * f;
        float* zetax = zetay + 2 * f;
        float* v2dt2 = zetax + 2 * f;
        float* prof  = v2dt2 + f;
        unsigned* srcmask = (unsigned*)(prof + 2 * LST);
        unsigned long long* recmask = (unsigned long long*)(srcmask + 2 * f);
        const long total_words = 23 * f + 2 * LST;
        zero_kernel<<<4096, 256, 0, stream>>>(base, total_words);
        populateL_kernel<<<(NYP_ * NXP_ + 255) / 256, 256, 0, stream>>>(
            v, srcloc, recloc, v2dt2, prof, srcmask, recmask);
        dim3 blk(64, 4, 1);
        dim3 grd((NXP_ + 63) / 64, (NYP_ + 3) / 4, NSHOT_);
        for (int t = 0; t < NTT; t++) {
            const float* wc  = (t & 1) ? wf1 : wf0;
            float*       wn  = (t & 1) ? wf0 : wf1;
            const float* pyr = (t & 1) ? psiy1 : psiy0;
            float*       pyw = (t & 1) ? psiy0 : psiy1;
            const float* pxr = (t & 1) ? psix1 : psix0;
            float*       pxw = (t & 1) ? psix0 : psix1;
            stepL_kernel<<<grd, blk, 0, stream>>>(wc, wn, pyr, pyw, pxr, pxw,
                                                  zetay, zetax, v2dt2, prof,
                                                  srcmask, recmask, amps, out, t);
        }
    }
}